// Round 9
// baseline (42.810 us; speedup 1.0000x reference)
//
#include <hip/hip_runtime.h>

#define NN 4096
#define HID 512
#define DD 64
#define SLOPE 0.2f
// hierarchy: 8 rows/chunk, 8 chunks/seg (64 rows), 8 segs/block (512 rows), 8 blocks
#define NCHUNK 512
#define NSEG 64
#define NBLK8 8

// ---------------- kA: xt = x@W, s1 = xt@a1, s2 = xt@a2 -----------------------
// v3: 16 rows/block (grid 256, 2 blocks/CU via 64 KiB LDS). x slab (32 KiB)
// coalesced-staged; W in 4 k-chunks of 32 KiB -> W traffic halved vs v2.
__global__ __launch_bounds__(256) void kA_xt(
    const float* __restrict__ x, const float* __restrict__ W,
    const float* __restrict__ a,
    float* __restrict__ xt, float* __restrict__ s1, float* __restrict__ s2) {
  __shared__ float xs[16 * HID];           // 32 KiB: block's 16 rows of x
  __shared__ float Wc[128 * DD];           // 32 KiB: one k-chunk of W
  int tid = threadIdx.x;
  int w = tid >> 6, l = tid & 63;
  int i0 = blockIdx.x * 16;                // first row of block

  // stage x slab: 2048 float4, coalesced, all independent (8 per thread)
  {
    const float4* xg = (const float4*)(x + (size_t)i0 * HID);
    float4* xs4 = (float4*)xs;
#pragma unroll
    for (int j = 0; j < 8; ++j)
      xs4[j * 256 + tid] = xg[j * 256 + tid];
  }

  int r0 = w * 4;                          // this wave's 4 local rows
  float acc0 = 0.f, acc1 = 0.f, acc2 = 0.f, acc3 = 0.f;
  const float4* xs4 = (const float4*)xs;

#pragma unroll
  for (int c = 0; c < 4; ++c) {
    __syncthreads();                       // readers of previous chunk done
    // stage W chunk c: rows [c*128, c*128+128) -> 2048 float4
    {
      const float4* Wg = (const float4*)(W + (size_t)c * 128 * DD);
      float4* Wc4 = (float4*)Wc;
#pragma unroll
      for (int j = 0; j < 8; ++j)
        Wc4[j * 256 + tid] = Wg[j * 256 + tid];
    }
    __syncthreads();
#pragma unroll 4
    for (int k4 = 0; k4 < 32; ++k4) {      // float4 groups within chunk
      float4 xv0 = xs4[(r0 + 0) * (HID / 4) + c * 32 + k4];
      float4 xv1 = xs4[(r0 + 1) * (HID / 4) + c * 32 + k4];
      float4 xv2 = xs4[(r0 + 2) * (HID / 4) + c * 32 + k4];
      float4 xv3 = xs4[(r0 + 3) * (HID / 4) + c * 32 + k4];
      int k = k4 * 4;
      float w0 = Wc[(k + 0) * DD + l];
      float w1 = Wc[(k + 1) * DD + l];
      float w2 = Wc[(k + 2) * DD + l];
      float w3 = Wc[(k + 3) * DD + l];
      acc0 = fmaf(xv0.x, w0, acc0); acc0 = fmaf(xv0.y, w1, acc0);
      acc0 = fmaf(xv0.z, w2, acc0); acc0 = fmaf(xv0.w, w3, acc0);
      acc1 = fmaf(xv1.x, w0, acc1); acc1 = fmaf(xv1.y, w1, acc1);
      acc1 = fmaf(xv1.z, w2, acc1); acc1 = fmaf(xv1.w, w3, acc1);
      acc2 = fmaf(xv2.x, w0, acc2); acc2 = fmaf(xv2.y, w1, acc2);
      acc2 = fmaf(xv2.z, w2, acc2); acc2 = fmaf(xv2.w, w3, acc2);
      acc3 = fmaf(xv3.x, w0, acc3); acc3 = fmaf(xv3.y, w1, acc3);
      acc3 = fmaf(xv3.z, w2, acc3); acc3 = fmaf(xv3.w, w3, acc3);
    }
  }
  xt[(i0 + r0 + 0) * DD + l] = acc0;
  xt[(i0 + r0 + 1) * DD + l] = acc1;
  xt[(i0 + r0 + 2) * DD + l] = acc2;
  xt[(i0 + r0 + 3) * DD + l] = acc3;
  float a1 = a[l], a2 = a[DD + l];
  float p10 = acc0 * a1, p20 = acc0 * a2;
  float p11 = acc1 * a1, p21 = acc1 * a2;
  float p12 = acc2 * a1, p22 = acc2 * a2;
  float p13 = acc3 * a1, p23 = acc3 * a2;
#pragma unroll
  for (int off = 32; off >= 1; off >>= 1) {
    p10 += __shfl_xor(p10, off, 64); p20 += __shfl_xor(p20, off, 64);
    p11 += __shfl_xor(p11, off, 64); p21 += __shfl_xor(p21, off, 64);
    p12 += __shfl_xor(p12, off, 64); p22 += __shfl_xor(p22, off, 64);
    p13 += __shfl_xor(p13, off, 64); p23 += __shfl_xor(p23, off, 64);
  }
  if (l == 0) {
    s1[i0 + r0 + 0] = p10; s2[i0 + r0 + 0] = p20;
    s1[i0 + r0 + 1] = p11; s2[i0 + r0 + 1] = p21;
    s1[i0 + r0 + 2] = p12; s2[i0 + r0 + 2] = p22;
    s1[i0 + r0 + 3] = p13; s2[i0 + r0 + 3] = p23;
  }
}

// ---------------- kB: rank-by-count + split index --------------------------
// 256 blocks x 256 thr. Block b handles elements/rows b*16..b*16+15:
//  rank of s2[e] among all s2 (stable) -> s2s, perm
//  kidx[i] = #{j : s2[j] <= -s1[i]}  (split point for row i)
__global__ __launch_bounds__(256) void kB_rank(
    const float* __restrict__ s2, const float* __restrict__ s1,
    float* __restrict__ s2s, int* __restrict__ perm, int* __restrict__ kidx) {
  __shared__ float keys[NN];     // 16 KiB
  __shared__ int pc[16][17];
  __shared__ int pk[16][17];
  int tid = threadIdx.x, b = blockIdx.x;
  const float4* s4 = (const float4*)s2;
  float4* kk = (float4*)keys;
#pragma unroll
  for (int u = 0; u < NN / 4 / 256; ++u)
    kk[u * 256 + tid] = s4[u * 256 + tid];
  __syncthreads();
  int el = tid & 15, rep = tid >> 4;
  int e = b * 16 + el;
  float ke = keys[e];
  float te = -s1[e];
  const float4* k4p = (const float4*)keys;
  int cnt = 0, ck = 0;
#pragma unroll 4
  for (int q4 = rep * 64; q4 < rep * 64 + 64; ++q4) {
    float4 kv = k4p[q4];
    int q = q4 * 4;
    cnt += (kv.x < ke || (kv.x == ke && q + 0 < e)) ? 1 : 0;
    cnt += (kv.y < ke || (kv.y == ke && q + 1 < e)) ? 1 : 0;
    cnt += (kv.z < ke || (kv.z == ke && q + 2 < e)) ? 1 : 0;
    cnt += (kv.w < ke || (kv.w == ke && q + 3 < e)) ? 1 : 0;
    ck += (kv.x <= te) ? 1 : 0;
    ck += (kv.y <= te) ? 1 : 0;
    ck += (kv.z <= te) ? 1 : 0;
    ck += (kv.w <= te) ? 1 : 0;
  }
  pc[rep][el] = cnt;
  pk[rep][el] = ck;
  __syncthreads();
  if (tid < 16) {
    int rank = 0, kx = 0;
#pragma unroll
    for (int r = 0; r < 16; ++r) { rank += pc[r][tid]; kx += pk[r][tid]; }
    s2s[rank] = keys[b * 16 + tid];
    perm[rank] = b * 16 + tid;
    kidx[b * 16 + tid] = kx;
  }
}

// ---------------- kC: hierarchical sums (chunk/seg/block) + exp pairs --------
// 8 blocks x 512 thr (8 waves). Block B owns sorted rows [B*512, B*512+512).
// Wave w owns seg s = B*8+w (64 rows = 8 chunks of 8).
__global__ __launch_bounds__(512) void kC_sums(
    const float* __restrict__ xt, const float* __restrict__ s2s,
    const int* __restrict__ perm,
    float2* __restrict__ EPN,
    float* __restrict__ CSP, float* __restrict__ CSN, float2* __restrict__ CZ,
    float* __restrict__ SGP, float* __restrict__ SGN, float2* __restrict__ SZ,
    float* __restrict__ BSP, float* __restrict__ BSN, float2* __restrict__ BZ) {
  __shared__ float2 evL[512];        // per-row (eP,eN) for the block's rows
  __shared__ float segPL[8][64], segNL[8][64];
  __shared__ float2 szL[8];
  int tid = threadIdx.x, w = tid >> 6, l = tid & 63, B = blockIdx.x;
  int segBase = B * 512 + w * 64;    // first sorted row of this wave's seg
  int seg = B * 8 + w;

  // per-row exp pair (lane-parallel: one row per lane)
  int row = segBase + l;
  float key = s2s[row];
  float eP = expf(key);
  float eN = expf(SLOPE * key);
  EPN[row] = make_float2(eP, eN);
  evL[w * 64 + l] = make_float2(eP, eN);
  int pmv = perm[row];               // this lane's row's source index

  // Z sums via shfl-xor tree: chunk level (width 8), then seg level
  float zp = eP, zn = eN;
#pragma unroll
  for (int off = 1; off <= 4; off <<= 1) {
    zp += __shfl_xor(zp, off, 64);
    zn += __shfl_xor(zn, off, 64);
  }
  if ((l & 7) == 0) CZ[seg * 8 + (l >> 3)] = make_float2(zp, zn);
#pragma unroll
  for (int off = 8; off <= 32; off <<= 1) {
    zp += __shfl_xor(zp, off, 64);
    zn += __shfl_xor(zn, off, 64);
  }
  if (l == 0) { SZ[seg] = make_float2(zp, zn); szL[w] = make_float2(zp, zn); }

  // chunk sums (vector, lane = dim d); seg accumulation
  float segP = 0.f, segN = 0.f;
#pragma unroll
  for (int c = 0; c < 8; ++c) {
    float cP = 0.f, cN = 0.f;
#pragma unroll
    for (int rr = 0; rr < 8; ++rr) {
      int pm = __shfl(pmv, c * 8 + rr, 64);
      float xv = xt[pm * DD + l];
      float2 ev = evL[w * 64 + c * 8 + rr];
      cP = fmaf(ev.x, xv, cP);
      cN = fmaf(ev.y, xv, cN);
    }
    CSP[(seg * 8 + c) * DD + l] = cP;
    CSN[(seg * 8 + c) * DD + l] = cN;
    segP += cP; segN += cN;
  }
  SGP[seg * DD + l] = segP;
  SGN[seg * DD + l] = segN;
  segPL[w][l] = segP; segNL[w][l] = segN;
  __syncthreads();

  // block totals (wave 0)
  if (w == 0) {
    float bP = 0.f, bN = 0.f;
#pragma unroll
    for (int s = 0; s < 8; ++s) { bP += segPL[s][l]; bN += segNL[s][l]; }
    BSP[B * DD + l] = bP;
    BSN[B * DD + l] = bN;
    if (l == 0) {
      float2 bz = make_float2(0.f, 0.f);
#pragma unroll
      for (int s = 0; s < 8; ++s) { bz.x += szL[s].x; bz.y += szL[s].y; }
      BZ[B] = bz;
    }
  }
}

// ---------------- kD: per-row output from hierarchical partials --------------
// 256 blocks x 256 thr; 4 rows per wave (lane = dim d).
__global__ __launch_bounds__(256) void kD_out(
    const float* __restrict__ xt, const float* __restrict__ s1,
    const int* __restrict__ perm, const int* __restrict__ kidx,
    const float2* __restrict__ EPN,
    const float* __restrict__ CSP, const float* __restrict__ CSN,
    const float2* __restrict__ CZ,
    const float* __restrict__ SGP, const float* __restrict__ SGN,
    const float2* __restrict__ SZ,
    const float* __restrict__ BSP, const float* __restrict__ BSN,
    const float2* __restrict__ BZ,
    float* __restrict__ out) {
  int tid = threadIdx.x, w = tid >> 6, l = tid & 63, b = blockIdx.x;
  int i = b * 16 + w * 4 + (l & 3);
  float s1v = s1[i];
  int kq = kidx[i];

  // grand totals (P side only needed)
  float totP = 0.f, totZ = 0.f;
#pragma unroll
  for (int j = 0; j < 8; ++j) {
    totP += BSP[j * DD + l];
    totZ += BZ[j].x;
  }

#pragma unroll
  for (int q = 0; q < 4; ++q) {
    int kk_ = __shfl(kq, q, 64);
    float s1q = __shfl(s1v, q, 64);
    float wP = expf(s1q);
    float wN = expf(SLOPE * s1q);
    float FPk = 0.f, FNk = 0.f, ZPk = 0.f, ZNk = 0.f;
    if (kk_ > 0) {
      int r = kk_ - 1;
      int br = r >> 9, sr = (r >> 6) & 7, cr = (r >> 3) & 7;
      int segg = r >> 6, base = r & ~7, rlim = r & 7;
      // full blocks below
#pragma unroll
      for (int j = 0; j < 7; ++j) {
        float vP = BSP[j * DD + l], vN = BSN[j * DD + l];
        float2 z = BZ[j];
        bool p = j < br;
        FPk += p ? vP : 0.f; FNk += p ? vN : 0.f;
        ZPk += p ? z.x : 0.f; ZNk += p ? z.y : 0.f;
      }
      // full segs below within block br
#pragma unroll
      for (int j = 0; j < 7; ++j) {
        int idx = (br << 3) + j;
        float vP = SGP[idx * DD + l], vN = SGN[idx * DD + l];
        float2 z = SZ[idx];
        bool p = j < sr;
        FPk += p ? vP : 0.f; FNk += p ? vN : 0.f;
        ZPk += p ? z.x : 0.f; ZNk += p ? z.y : 0.f;
      }
      // full chunks below within seg
#pragma unroll
      for (int j = 0; j < 7; ++j) {
        int idx = (segg << 3) + j;
        float vP = CSP[idx * DD + l], vN = CSN[idx * DD + l];
        float2 z = CZ[idx];
        bool p = j < cr;
        FPk += p ? vP : 0.f; FNk += p ? vN : 0.f;
        ZPk += p ? z.x : 0.f; ZNk += p ? z.y : 0.f;
      }
      // rows within chunk
#pragma unroll
      for (int j = 0; j < 8; ++j) {
        int rw = base + j;
        float2 ev = EPN[rw];
        int pm = perm[rw];
        float xv = xt[pm * DD + l];
        bool p = j <= rlim;
        FPk = fmaf(p ? ev.x : 0.f, xv, FPk);
        FNk = fmaf(p ? ev.y : 0.f, xv, FNk);
        ZPk += p ? ev.x : 0.f; ZNk += p ? ev.y : 0.f;
      }
    }
    float num = wP * (totP - FPk) + wN * FNk;
    float den = wP * (totZ - ZPk) + wN * ZNk;
    out[(b * 16 + w * 4 + q) * DD + l] = num / den;
  }
}

extern "C" void kernel_launch(void* const* d_in, const int* in_sizes, int n_in,
                              void* d_out, int out_size, void* d_ws, size_t ws_size,
                              hipStream_t stream) {
  const float* x = (const float*)d_in[0];
  const float* W = (const float*)d_in[1];
  const float* a = (const float*)d_in[2];
  float* out = (float*)d_out;

  float* ws = (float*)d_ws;
  float*  xt   = ws;                     // 262144
  float*  s1   = xt + NN * DD;           // 4096
  float*  s2   = s1 + NN;                // 4096
  float*  s2s  = s2 + NN;                // 4096
  int*    perm = (int*)(s2s + NN);       // 4096
  int*    kidx = perm + NN;              // 4096
  float2* EPN  = (float2*)(kidx + NN);   // 4096 float2
  float*  CSP  = (float*)(EPN + NN);     // 512*64
  float*  CSN  = CSP + NCHUNK * DD;      // 512*64
  float2* CZ   = (float2*)(CSN + NCHUNK * DD);   // 512 float2
  float*  SGP  = (float*)(CZ + NCHUNK);  // 64*64
  float*  SGN  = SGP + NSEG * DD;        // 64*64
  float2* SZ   = (float2*)(SGN + NSEG * DD);     // 64 float2
  float*  BSP  = (float*)(SZ + NSEG);    // 8*64
  float*  BSN  = BSP + NBLK8 * DD;       // 8*64
  float2* BZ   = (float2*)(BSN + NBLK8 * DD);    // 8 float2

  kA_xt<<<NN / 16, 256, 0, stream>>>(x, W, a, xt, s1, s2);
  kB_rank<<<NN / 16, 256, 0, stream>>>(s2, s1, s2s, perm, kidx);
  kC_sums<<<NBLK8, 512, 0, stream>>>(xt, s2s, perm, EPN, CSP, CSN, CZ,
                                     SGP, SGN, SZ, BSP, BSN, BZ);
  kD_out<<<NN / 16, 256, 0, stream>>>(xt, s1, perm, kidx, EPN, CSP, CSN, CZ,
                                      SGP, SGN, SZ, BSP, BSN, BZ, out);
}

// Round 10
// 41.679 us; speedup vs baseline: 1.0272x; 1.0272x over previous
//
#include <hip/hip_runtime.h>

#define NN 4096
#define HID 512
#define DD 64
#define SLOPE 0.2f
// hierarchy: 8 rows/chunk, 8 chunks/seg (64 rows), 8 segs/block (512 rows), 8 blocks
#define NCHUNK 512
#define NSEG 64
#define NBLK8 8

// ---------------- kA: xt = x@W, s1 = xt@a1, s2 = xt@a2 -----------------------
// v2 (best measured, r8): 8 rows/block (grid 512, 2 blocks/CU), x slab
// coalesced-staged in LDS, W in 4 k-chunks of 32 KiB. 2 rows/wave.
__global__ __launch_bounds__(256) void kA_xt(
    const float* __restrict__ x, const float* __restrict__ W,
    const float* __restrict__ a,
    float* __restrict__ xt, float* __restrict__ s1, float* __restrict__ s2) {
  __shared__ float xs[8 * HID];            // 16 KiB: block's 8 rows of x
  __shared__ float Wc[128 * DD];           // 32 KiB: one k-chunk of W
  int tid = threadIdx.x;
  int w = tid >> 6, l = tid & 63;
  int i0 = blockIdx.x * 8;                 // first row of block

  // stage x slab: 1024 float4, coalesced, all independent
  {
    const float4* xg = (const float4*)(x + (size_t)i0 * HID);
    float4* xs4 = (float4*)xs;
#pragma unroll
    for (int j = 0; j < 4; ++j)
      xs4[j * 256 + tid] = xg[j * 256 + tid];
  }

  int r0 = w * 2, r1 = w * 2 + 1;          // this wave's rows (local)
  float acc0 = 0.f, acc1 = 0.f;
  const float4* xs4 = (const float4*)xs;

#pragma unroll
  for (int c = 0; c < 4; ++c) {
    __syncthreads();                       // readers of previous chunk done
    // stage W chunk c: rows [c*128, c*128+128) of W -> 2048 float4
    {
      const float4* Wg = (const float4*)(W + (size_t)c * 128 * DD);
      float4* Wc4 = (float4*)Wc;
#pragma unroll
      for (int j = 0; j < 8; ++j)
        Wc4[j * 256 + tid] = Wg[j * 256 + tid];
    }
    __syncthreads();
#pragma unroll 4
    for (int k4 = 0; k4 < 32; ++k4) {      // float4 groups within chunk
      float4 xv0 = xs4[r0 * (HID / 4) + c * 32 + k4];  // broadcast b128
      float4 xv1 = xs4[r1 * (HID / 4) + c * 32 + k4];
      int k = k4 * 4;
      float w0 = Wc[(k + 0) * DD + l];
      float w1 = Wc[(k + 1) * DD + l];
      float w2 = Wc[(k + 2) * DD + l];
      float w3 = Wc[(k + 3) * DD + l];
      acc0 = fmaf(xv0.x, w0, acc0); acc0 = fmaf(xv0.y, w1, acc0);
      acc0 = fmaf(xv0.z, w2, acc0); acc0 = fmaf(xv0.w, w3, acc0);
      acc1 = fmaf(xv1.x, w0, acc1); acc1 = fmaf(xv1.y, w1, acc1);
      acc1 = fmaf(xv1.z, w2, acc1); acc1 = fmaf(xv1.w, w3, acc1);
    }
  }
  xt[(i0 + r0) * DD + l] = acc0;
  xt[(i0 + r1) * DD + l] = acc1;
  float a1 = a[l], a2 = a[DD + l];
  float p10 = acc0 * a1, p20 = acc0 * a2;
  float p11 = acc1 * a1, p21 = acc1 * a2;
#pragma unroll
  for (int off = 32; off >= 1; off >>= 1) {
    p10 += __shfl_xor(p10, off, 64); p20 += __shfl_xor(p20, off, 64);
    p11 += __shfl_xor(p11, off, 64); p21 += __shfl_xor(p21, off, 64);
  }
  if (l == 0) {
    s1[i0 + r0] = p10; s2[i0 + r0] = p20;
    s1[i0 + r1] = p11; s2[i0 + r1] = p21;
  }
}

// ---------------- kB: rank-by-count + split index --------------------------
// 256 blocks x 256 thr. Block b handles elements/rows b*16..b*16+15:
//  rank of s2[e] among all s2 (stable) -> s2s, perm
//  kidx[i] = #{j : s2[j] <= -s1[i]}  (split point for row i)
__global__ __launch_bounds__(256) void kB_rank(
    const float* __restrict__ s2, const float* __restrict__ s1,
    float* __restrict__ s2s, int* __restrict__ perm, int* __restrict__ kidx) {
  __shared__ float keys[NN];     // 16 KiB
  __shared__ int pc[16][17];
  __shared__ int pk[16][17];
  int tid = threadIdx.x, b = blockIdx.x;
  const float4* s4 = (const float4*)s2;
  float4* kk = (float4*)keys;
#pragma unroll
  for (int u = 0; u < NN / 4 / 256; ++u)
    kk[u * 256 + tid] = s4[u * 256 + tid];
  __syncthreads();
  int el = tid & 15, rep = tid >> 4;
  int e = b * 16 + el;
  float ke = keys[e];
  float te = -s1[e];
  const float4* k4p = (const float4*)keys;
  int cnt = 0, ck = 0;
#pragma unroll 4
  for (int q4 = rep * 64; q4 < rep * 64 + 64; ++q4) {
    float4 kv = k4p[q4];
    int q = q4 * 4;
    cnt += (kv.x < ke || (kv.x == ke && q + 0 < e)) ? 1 : 0;
    cnt += (kv.y < ke || (kv.y == ke && q + 1 < e)) ? 1 : 0;
    cnt += (kv.z < ke || (kv.z == ke && q + 2 < e)) ? 1 : 0;
    cnt += (kv.w < ke || (kv.w == ke && q + 3 < e)) ? 1 : 0;
    ck += (kv.x <= te) ? 1 : 0;
    ck += (kv.y <= te) ? 1 : 0;
    ck += (kv.z <= te) ? 1 : 0;
    ck += (kv.w <= te) ? 1 : 0;
  }
  pc[rep][el] = cnt;
  pk[rep][el] = ck;
  __syncthreads();
  if (tid < 16) {
    int rank = 0, kx = 0;
#pragma unroll
    for (int r = 0; r < 16; ++r) { rank += pc[r][tid]; kx += pk[r][tid]; }
    s2s[rank] = keys[b * 16 + tid];
    perm[rank] = b * 16 + tid;
    kidx[b * 16 + tid] = kx;
  }
}

// ---------------- kC: hierarchical sums (chunk/seg/block) + exp pairs --------
// 8 blocks x 512 thr (8 waves). Block B owns sorted rows [B*512, B*512+512).
// Wave w owns seg s = B*8+w (64 rows = 8 chunks of 8).
__global__ __launch_bounds__(512) void kC_sums(
    const float* __restrict__ xt, const float* __restrict__ s2s,
    const int* __restrict__ perm,
    float2* __restrict__ EPN,
    float* __restrict__ CSP, float* __restrict__ CSN, float2* __restrict__ CZ,
    float* __restrict__ SGP, float* __restrict__ SGN, float2* __restrict__ SZ,
    float* __restrict__ BSP, float* __restrict__ BSN, float2* __restrict__ BZ) {
  __shared__ float2 evL[512];        // per-row (eP,eN) for the block's rows
  __shared__ float segPL[8][64], segNL[8][64];
  __shared__ float2 szL[8];
  int tid = threadIdx.x, w = tid >> 6, l = tid & 63, B = blockIdx.x;
  int segBase = B * 512 + w * 64;    // first sorted row of this wave's seg
  int seg = B * 8 + w;

  // per-row exp pair (lane-parallel: one row per lane)
  int row = segBase + l;
  float key = s2s[row];
  float eP = expf(key);
  float eN = expf(SLOPE * key);
  EPN[row] = make_float2(eP, eN);
  evL[w * 64 + l] = make_float2(eP, eN);
  int pmv = perm[row];               // this lane's row's source index

  // Z sums via shfl-xor tree: chunk level (width 8), then seg level
  float zp = eP, zn = eN;
#pragma unroll
  for (int off = 1; off <= 4; off <<= 1) {
    zp += __shfl_xor(zp, off, 64);
    zn += __shfl_xor(zn, off, 64);
  }
  if ((l & 7) == 0) CZ[seg * 8 + (l >> 3)] = make_float2(zp, zn);
#pragma unroll
  for (int off = 8; off <= 32; off <<= 1) {
    zp += __shfl_xor(zp, off, 64);
    zn += __shfl_xor(zn, off, 64);
  }
  if (l == 0) { SZ[seg] = make_float2(zp, zn); szL[w] = make_float2(zp, zn); }

  // chunk sums (vector, lane = dim d); seg accumulation
  float segP = 0.f, segN = 0.f;
#pragma unroll
  for (int c = 0; c < 8; ++c) {
    float cP = 0.f, cN = 0.f;
#pragma unroll
    for (int rr = 0; rr < 8; ++rr) {
      int pm = __shfl(pmv, c * 8 + rr, 64);
      float xv = xt[pm * DD + l];
      float2 ev = evL[w * 64 + c * 8 + rr];
      cP = fmaf(ev.x, xv, cP);
      cN = fmaf(ev.y, xv, cN);
    }
    CSP[(seg * 8 + c) * DD + l] = cP;
    CSN[(seg * 8 + c) * DD + l] = cN;
    segP += cP; segN += cN;
  }
  SGP[seg * DD + l] = segP;
  SGN[seg * DD + l] = segN;
  segPL[w][l] = segP; segNL[w][l] = segN;
  __syncthreads();

  // block totals (wave 0)
  if (w == 0) {
    float bP = 0.f, bN = 0.f;
#pragma unroll
    for (int s = 0; s < 8; ++s) { bP += segPL[s][l]; bN += segNL[s][l]; }
    BSP[B * DD + l] = bP;
    BSN[B * DD + l] = bN;
    if (l == 0) {
      float2 bz = make_float2(0.f, 0.f);
#pragma unroll
      for (int s = 0; s < 8; ++s) { bz.x += szL[s].x; bz.y += szL[s].y; }
      BZ[B] = bz;
    }
  }
}

// ---------------- kD: per-row output from hierarchical partials --------------
// 256 blocks x 256 thr; 4 rows per wave (lane = dim d).
__global__ __launch_bounds__(256) void kD_out(
    const float* __restrict__ xt, const float* __restrict__ s1,
    const int* __restrict__ perm, const int* __restrict__ kidx,
    const float2* __restrict__ EPN,
    const float* __restrict__ CSP, const float* __restrict__ CSN,
    const float2* __restrict__ CZ,
    const float* __restrict__ SGP, const float* __restrict__ SGN,
    const float2* __restrict__ SZ,
    const float* __restrict__ BSP, const float* __restrict__ BSN,
    const float2* __restrict__ BZ,
    float* __restrict__ out) {
  int tid = threadIdx.x, w = tid >> 6, l = tid & 63, b = blockIdx.x;
  int i = b * 16 + w * 4 + (l & 3);
  float s1v = s1[i];
  int kq = kidx[i];

  // grand totals (P side only needed)
  float totP = 0.f, totZ = 0.f;
#pragma unroll
  for (int j = 0; j < 8; ++j) {
    totP += BSP[j * DD + l];
    totZ += BZ[j].x;
  }

#pragma unroll
  for (int q = 0; q < 4; ++q) {
    int kk_ = __shfl(kq, q, 64);
    float s1q = __shfl(s1v, q, 64);
    float wP = expf(s1q);
    float wN = expf(SLOPE * s1q);
    float FPk = 0.f, FNk = 0.f, ZPk = 0.f, ZNk = 0.f;
    if (kk_ > 0) {
      int r = kk_ - 1;
      int br = r >> 9, sr = (r >> 6) & 7, cr = (r >> 3) & 7;
      int segg = r >> 6, base = r & ~7, rlim = r & 7;
      // full blocks below
#pragma unroll
      for (int j = 0; j < 7; ++j) {
        float vP = BSP[j * DD + l], vN = BSN[j * DD + l];
        float2 z = BZ[j];
        bool p = j < br;
        FPk += p ? vP : 0.f; FNk += p ? vN : 0.f;
        ZPk += p ? z.x : 0.f; ZNk += p ? z.y : 0.f;
      }
      // full segs below within block br
#pragma unroll
      for (int j = 0; j < 7; ++j) {
        int idx = (br << 3) + j;
        float vP = SGP[idx * DD + l], vN = SGN[idx * DD + l];
        float2 z = SZ[idx];
        bool p = j < sr;
        FPk += p ? vP : 0.f; FNk += p ? vN : 0.f;
        ZPk += p ? z.x : 0.f; ZNk += p ? z.y : 0.f;
      }
      // full chunks below within seg
#pragma unroll
      for (int j = 0; j < 7; ++j) {
        int idx = (segg << 3) + j;
        float vP = CSP[idx * DD + l], vN = CSN[idx * DD + l];
        float2 z = CZ[idx];
        bool p = j < cr;
        FPk += p ? vP : 0.f; FNk += p ? vN : 0.f;
        ZPk += p ? z.x : 0.f; ZNk += p ? z.y : 0.f;
      }
      // rows within chunk
#pragma unroll
      for (int j = 0; j < 8; ++j) {
        int rw = base + j;
        float2 ev = EPN[rw];
        int pm = perm[rw];
        float xv = xt[pm * DD + l];
        bool p = j <= rlim;
        FPk = fmaf(p ? ev.x : 0.f, xv, FPk);
        FNk = fmaf(p ? ev.y : 0.f, xv, FNk);
        ZPk += p ? ev.x : 0.f; ZNk += p ? ev.y : 0.f;
      }
    }
    float num = wP * (totP - FPk) + wN * FNk;
    float den = wP * (totZ - ZPk) + wN * ZNk;
    out[(b * 16 + w * 4 + q) * DD + l] = num / den;
  }
}

extern "C" void kernel_launch(void* const* d_in, const int* in_sizes, int n_in,
                              void* d_out, int out_size, void* d_ws, size_t ws_size,
                              hipStream_t stream) {
  const float* x = (const float*)d_in[0];
  const float* W = (const float*)d_in[1];
  const float* a = (const float*)d_in[2];
  float* out = (float*)d_out;

  float* ws = (float*)d_ws;
  float*  xt   = ws;                     // 262144
  float*  s1   = xt + NN * DD;           // 4096
  float*  s2   = s1 + NN;                // 4096
  float*  s2s  = s2 + NN;                // 4096
  int*    perm = (int*)(s2s + NN);       // 4096
  int*    kidx = perm + NN;              // 4096
  float2* EPN  = (float2*)(kidx + NN);   // 4096 float2
  float*  CSP  = (float*)(EPN + NN);     // 512*64
  float*  CSN  = CSP + NCHUNK * DD;      // 512*64
  float2* CZ   = (float2*)(CSN + NCHUNK * DD);   // 512 float2
  float*  SGP  = (float*)(CZ + NCHUNK);  // 64*64
  float*  SGN  = SGP + NSEG * DD;        // 64*64
  float2* SZ   = (float2*)(SGN + NSEG * DD);     // 64 float2
  float*  BSP  = (float*)(SZ + NSEG);    // 8*64
  float*  BSN  = BSP + NBLK8 * DD;       // 8*64
  float2* BZ   = (float2*)(BSN + NBLK8 * DD);    // 8 float2

  kA_xt<<<NN / 8, 256, 0, stream>>>(x, W, a, xt, s1, s2);
  kB_rank<<<NN / 16, 256, 0, stream>>>(s2, s1, s2s, perm, kidx);
  kC_sums<<<NBLK8, 512, 0, stream>>>(xt, s2s, perm, EPN, CSP, CSN, CZ,
                                     SGP, SGN, SZ, BSP, BSN, BZ);
  kD_out<<<NN / 16, 256, 0, stream>>>(xt, s1, perm, kidx, EPN, CSP, CSN, CZ,
                                      SGP, SGN, SZ, BSP, BSN, BZ, out);
}